// Round 4
// baseline (165.563 us; speedup 1.0000x reference)
//
#include <hip/hip_runtime.h>

using u16    = unsigned short;
using f32x4  = __attribute__((ext_vector_type(4))) float;
using bf16x8 = __attribute__((ext_vector_type(8))) __bf16;

#define E_CNT 400000
#define G_CNT 1024
#define NROWS 401024   // E+G = 3133*128 exactly
#define NBLK  3133

// ws layout (bytes)
#define WS_NRBF   0u          // [65536][128] bf16 = 16777216
#define WS_GFBF   16777216u   // [1024][384] bf16  =   786432
#define WS_WT     17563648u   // [128][544] bf16   =   139264  (W cols as rows, K zero-padded 516..543)
#define WS_NME    17702912u   // [160] bf16        =      320
#define WS_BIAS   17703232u   // [128] f32         =      512

__device__ __forceinline__ u16 f2bf(float f) {
  unsigned u = __builtin_bit_cast(unsigned, f);
  return (u16)((u + 0x7fffu + ((u >> 16) & 1u)) >> 16);  // RNE
}

// ---------- precompute kernels ----------

__global__ __launch_bounds__(256) void k_conv_nr(const float4* __restrict__ in,
                                                 u16* __restrict__ out) {
  int i = blockIdx.x * 256 + threadIdx.x;
  float4 v = in[i];
  unsigned lo = (unsigned)f2bf(v.x) | ((unsigned)f2bf(v.y) << 16);
  unsigned hi = (unsigned)f2bf(v.z) | ((unsigned)f2bf(v.w) << 16);
  reinterpret_cast<uint2*>(out)[i] = make_uint2(lo, hi);
}

__global__ __launch_bounds__(128) void k_gf(const float* __restrict__ imr,
                                            const float* __restrict__ pgr,
                                            const float* __restrict__ nr,
                                            const int* __restrict__ focus,
                                            u16* __restrict__ gfbf) {
  int g = blockIdx.x, t = threadIdx.x;
  int fi = focus[g];
  u16* row = gfbf + (size_t)g * 384;
  row[t]       = f2bf(imr[(size_t)g * 128 + t]);
  row[128 + t] = f2bf(pgr[(size_t)g * 128 + t]);
  row[256 + t] = f2bf(nr[(size_t)fi * 128 + t]);
}

__global__ __launch_bounds__(256) void k_wt(const float* __restrict__ sW1,
                                            const float* __restrict__ tW1,
                                            u16* __restrict__ wt) {
  int idx = blockIdx.x * 256 + threadIdx.x;
  if (idx >= 128 * 544) return;
  int col = idx / 544;
  int k = idx - col * 544;
  float v = 0.f;
  if (k < 516) v = (col < 64) ? sW1[(size_t)k * 64 + col] : tW1[(size_t)k * 64 + (col - 64)];
  wt[idx] = f2bf(v);
}

__global__ __launch_bounds__(256) void k_misc(const float* __restrict__ nme,
                                              const float* __restrict__ sb1,
                                              const float* __restrict__ tb1,
                                              u16* __restrict__ nmebf,
                                              float* __restrict__ bias) {
  int t = threadIdx.x;
  if (t < 160) nmebf[t] = (t < 132) ? f2bf(nme[t]) : (u16)0;
  if (t < 64) bias[t] = sb1[t];
  else if (t < 128) bias[t] = tb1[t - 64];
}

// ---------- zero-LDS, zero-barrier gather-GEMM + dual epilogue ----------
// One wave per 64 output rows; wave tile 64x128 (acc 4x8 f32x4 = 128 VGPR).
// A fragments gathered straight to registers via per-lane row pointers
// (lane(lr,lg) holds A[row=lr][k=lg*8..+7] -> addr = rowptr + c*64 + lg*16);
// B fragments loaded from the 139 KB L2-hot WT the same way. 17 K-steps fully
// unrolled -> immediate offsets, compiler-pipelined counted vmcnt, no
// barriers, no LDS, waves fully independent.
__global__ __launch_bounds__(128, 2) void fused_mlp(
    const u16* __restrict__ NRbf, const u16* __restrict__ GFbf,
    const u16* __restrict__ WT, const u16* __restrict__ NMEbf,
    const float* __restrict__ bias128,
    const int* __restrict__ tgt, const int* __restrict__ n2g,
    const float* __restrict__ feats, const float* __restrict__ dtab,
    const float* __restrict__ sW2, const float* __restrict__ sb2,
    const float* __restrict__ tW2, const float* __restrict__ tb2,
    float* __restrict__ out0, float* __restrict__ out1) {
  const int tid = threadIdx.x;
  const int l = tid & 63, w = tid >> 6;
  const int lr = l & 15, lg = l >> 4;
  const int row0 = blockIdx.x * 128 + w * 64;       // wave's first row
  const bool edge = (row0 < E_CNT);                 // waves homogeneous (400000%64==0)

  // per-lane A row pointers (already offset by lg*16 k-slot)
  const char* pGF[4];
  const char* pNR[4];
  int rowm[4];
#pragma unroll
  for (int fm = 0; fm < 4; ++fm) {
    int m = row0 + fm * 16 + lr;
    rowm[fm] = m;
    if (edge) {
      int t = tgt[m];
      int g = n2g[t];
      pGF[fm] = (const char*)GFbf + (size_t)g * 768 + lg * 16;
      pNR[fm] = (const char*)NRbf + (size_t)t * 256 + lg * 16;
    } else {
      pGF[fm] = (const char*)GFbf + (size_t)(m - E_CNT) * 768 + lg * 16;
      pNR[fm] = (const char*)NMEbf + lg * 16;  // NME zero-padded to 160
    }
  }
  const char* pB[8];
#pragma unroll
  for (int fn = 0; fn < 8; ++fn)
    pB[fn] = (const char*)WT + (size_t)(fn * 16 + lr) * 1088 + lg * 16;

  f32x4 acc[4][8];
#pragma unroll
  for (int i = 0; i < 4; ++i)
#pragma unroll
    for (int j = 0; j < 8; ++j) acc[i][j] = (f32x4){0.f, 0.f, 0.f, 0.f};

  // ---- K-chunks 0..15 (k = c*32..c*32+31), fully unrolled ----
#pragma unroll
  for (int c = 0; c < 16; ++c) {
    bf16x8 aF[4], bF[8];
#pragma unroll
    for (int fm = 0; fm < 4; ++fm)
      aF[fm] = (c < 12) ? *(const bf16x8*)(pGF[fm] + c * 64)
                        : *(const bf16x8*)(pNR[fm] + (c - 12) * 64);
#pragma unroll
    for (int fn = 0; fn < 8; ++fn)
      bF[fn] = *(const bf16x8*)(pB[fn] + c * 64);
#pragma unroll
    for (int fm = 0; fm < 4; ++fm)
#pragma unroll
      for (int fn = 0; fn < 8; ++fn)
        acc[fm][fn] = __builtin_amdgcn_mfma_f32_16x16x32_bf16(aF[fm], bF[fn], acc[fm][fn], 0, 0, 0);
  }

  // ---- tail chunk c=16 (k 512..543): A built in registers ----
  {
    bf16x8 bF[8];
#pragma unroll
    for (int fn = 0; fn < 8; ++fn)
      bF[fn] = *(const bf16x8*)(pB[fn] + 16 * 64);  // WT zero-padded
#pragma unroll
    for (int fm = 0; fm < 4; ++fm) {
      union { u16 u[8]; bf16x8 v; } tt;
#pragma unroll
      for (int j = 0; j < 8; ++j) tt.u[j] = 0;
      if (lg == 0) {  // k=512..519: [dist_emb, f1, f2, f3, 0,0,0,0]
        if (edge) {
          const float4 f = *(const float4*)(feats + (size_t)rowm[fm] * 4);
          int td = (int)fminf(f.x, 9.0f);
          tt.u[0] = f2bf(dtab[td]); tt.u[1] = f2bf(f.y);
          tt.u[2] = f2bf(f.z);      tt.u[3] = f2bf(f.w);
        } else {
          tt.u[0] = NMEbf[128]; tt.u[1] = NMEbf[129];
          tt.u[2] = NMEbf[130]; tt.u[3] = NMEbf[131];
        }
      }
#pragma unroll
      for (int fn = 0; fn < 8; ++fn)
        acc[fm][fn] = __builtin_amdgcn_mfma_f32_16x16x32_bf16(tt.v, bF[fn], acc[fm][fn], 0, 0, 0);
    }
  }

  // ---- epilogues. C layout: col = fn*16+lr, row = fm*16 + lg*4 + rg ----
  // scorer head: hidden cols 0..63 = fn 0..3
  {
    float w2v[4], bb[4];
#pragma unroll
    for (int fn = 0; fn < 4; ++fn) {
      int hh = fn * 16 + lr;
      w2v[fn] = sW2[hh];
      bb[fn] = bias128[hh];
    }
    float b2 = sb2[0];
#pragma unroll
    for (int fm = 0; fm < 4; ++fm) {
      float p[4] = {0.f, 0.f, 0.f, 0.f};
#pragma unroll
      for (int fn = 0; fn < 4; ++fn)
#pragma unroll
        for (int rg = 0; rg < 4; ++rg)
          p[rg] += fmaxf(acc[fm][fn][rg] + bb[fn], 0.f) * w2v[fn];
#pragma unroll
      for (int rg = 0; rg < 4; ++rg)
#pragma unroll
        for (int m = 1; m < 16; m <<= 1) p[rg] += __shfl_xor(p[rg], m, 64);
      if (lr == 0) {
        int rbase = row0 + fm * 16 + lg * 4;
        float4 o = make_float4(p[0] + b2, p[1] + b2, p[2] + b2, p[3] + b2);
        *(float4*)(out0 + rbase) = o;
      }
    }
  }
  // type head: hidden cols 64..127 = fn 4..7 (edge waves only)
  if (edge) {
    float bb[4], tw0[4], tw1[4], tw2v[4];
#pragma unroll
    for (int fn = 0; fn < 4; ++fn) {
      int hh = fn * 16 + lr;
      bb[fn] = bias128[64 + hh];
      tw0[fn] = tW2[hh * 3 + 0];
      tw1[fn] = tW2[hh * 3 + 1];
      tw2v[fn] = tW2[hh * 3 + 2];
    }
    float tb0 = tb2[0], tb1 = tb2[1], tb2s = tb2[2];
#pragma unroll
    for (int fm = 0; fm < 4; ++fm) {
      float p0[4] = {0.f, 0.f, 0.f, 0.f}, p1[4] = {0.f, 0.f, 0.f, 0.f}, p2[4] = {0.f, 0.f, 0.f, 0.f};
#pragma unroll
      for (int fn = 0; fn < 4; ++fn)
#pragma unroll
        for (int rg = 0; rg < 4; ++rg) {
          float h = fmaxf(acc[fm][fn + 4][rg] + bb[fn], 0.f);
          p0[rg] += h * tw0[fn];
          p1[rg] += h * tw1[fn];
          p2[rg] += h * tw2v[fn];
        }
#pragma unroll
      for (int rg = 0; rg < 4; ++rg)
#pragma unroll
        for (int m = 1; m < 16; m <<= 1) {
          p0[rg] += __shfl_xor(p0[rg], m, 64);
          p1[rg] += __shfl_xor(p1[rg], m, 64);
          p2[rg] += __shfl_xor(p2[rg], m, 64);
        }
      if (lr == 0) {
        int rbase = row0 + fm * 16 + lg * 4;
        float* dst = out1 + (size_t)rbase * 3;  // 12 consecutive f32, 16B-aligned
        float v[12] = {p0[0] + tb0, p1[0] + tb1, p2[0] + tb2s,
                       p0[1] + tb0, p1[1] + tb1, p2[1] + tb2s,
                       p0[2] + tb0, p1[2] + tb1, p2[2] + tb2s,
                       p0[3] + tb0, p1[3] + tb1, p2[3] + tb2s};
        *(float4*)(dst + 0) = make_float4(v[0], v[1], v[2], v[3]);
        *(float4*)(dst + 4) = make_float4(v[4], v[5], v[6], v[7]);
        *(float4*)(dst + 8) = make_float4(v[8], v[9], v[10], v[11]);
      }
    }
  }
}

extern "C" void kernel_launch(void* const* d_in, const int* in_sizes, int n_in,
                              void* d_out, int out_size, void* d_ws, size_t ws_size,
                              hipStream_t stream) {
  const float* imr   = (const float*)d_in[0];
  const float* pgr   = (const float*)d_in[1];
  const float* nr    = (const float*)d_in[2];
  const int*   focus = (const int*)d_in[3];
  const int*   n2g   = (const int*)d_in[4];
  const int*   tgt   = (const int*)d_in[5];
  const float* feats = (const float*)d_in[6];
  const float* dtab  = (const float*)d_in[8];
  const float* nme   = (const float*)d_in[9];
  const float* sW1   = (const float*)d_in[10];
  const float* sb1   = (const float*)d_in[11];
  const float* sW2   = (const float*)d_in[12];
  const float* sb2   = (const float*)d_in[13];
  const float* tW1   = (const float*)d_in[14];
  const float* tb1   = (const float*)d_in[15];
  const float* tW2   = (const float*)d_in[16];
  const float* tb2   = (const float*)d_in[17];

  char* ws = (char*)d_ws;
  u16*   NRbf  = (u16*)(ws + WS_NRBF);
  u16*   GFbf  = (u16*)(ws + WS_GFBF);
  u16*   WT    = (u16*)(ws + WS_WT);
  u16*   NMEbf = (u16*)(ws + WS_NME);
  float* bias  = (float*)(ws + WS_BIAS);

  float* out0 = (float*)d_out;          // [401024]
  float* out1 = out0 + NROWS;           // [400000*3]

  k_conv_nr<<<8192, 256, 0, stream>>>((const float4*)nr, NRbf);
  k_gf<<<1024, 128, 0, stream>>>(imr, pgr, nr, focus, GFbf);
  k_wt<<<272, 256, 0, stream>>>(sW1, tW1, WT);
  k_misc<<<1, 256, 0, stream>>>(nme, sb1, tb1, NMEbf, bias);
  fused_mlp<<<NBLK, 128, 0, stream>>>(NRbf, GFbf, WT, NMEbf, bias, tgt, n2g, feats,
                                      dtab, sW2, sb2, tW2, tb2, out0, out1);
}

// Round 5
// 101.361 us; speedup vs baseline: 1.6334x; 1.6334x over previous
//
#include <hip/hip_runtime.h>

using u16    = unsigned short;
using f32x4  = __attribute__((ext_vector_type(4))) float;
using bf16x8 = __attribute__((ext_vector_type(8))) __bf16;

#define E_CNT 400000
#define G_CNT 1024
#define NROWS 401024   // E+G = 3133*128 exactly
#define NBLK  3133

// ws layout (bytes)
#define WS_NRBF   0u          // [65536][128] bf16 = 16777216
#define WS_GFBF   16777216u   // [1024][384] bf16  =   786432
#define WS_WTF    17563648u   // [17][8][64] x 16B =   139264  (B frags: chunk c, fn, lane)
#define WS_NME    17702912u   // [160] bf16        =      320
#define WS_BIAS   17703232u   // [128] f32         =      512

__device__ __forceinline__ u16 f2bf(float f) {
  unsigned u = __builtin_bit_cast(unsigned, f);
  return (u16)((u + 0x7fffu + ((u >> 16) & 1u)) >> 16);  // RNE
}

__device__ __forceinline__ void gload16(const void* g, void* l) {
  __builtin_amdgcn_global_load_lds((const __attribute__((address_space(1))) void*)g,
                                   (__attribute__((address_space(3))) void*)l, 16, 0, 0);
}

// ---------- precompute kernels ----------

__global__ __launch_bounds__(256) void k_conv_nr(const float4* __restrict__ in,
                                                 u16* __restrict__ out) {
  int i = blockIdx.x * 256 + threadIdx.x;
  float4 v = in[i];
  unsigned lo = (unsigned)f2bf(v.x) | ((unsigned)f2bf(v.y) << 16);
  unsigned hi = (unsigned)f2bf(v.z) | ((unsigned)f2bf(v.w) << 16);
  reinterpret_cast<uint2*>(out)[i] = make_uint2(lo, hi);
}

__global__ __launch_bounds__(128) void k_gf(const float* __restrict__ imr,
                                            const float* __restrict__ pgr,
                                            const float* __restrict__ nr,
                                            const int* __restrict__ focus,
                                            u16* __restrict__ gfbf) {
  int g = blockIdx.x, t = threadIdx.x;
  int fi = focus[g];
  u16* row = gfbf + (size_t)g * 384;
  row[t]       = f2bf(imr[(size_t)g * 128 + t]);
  row[128 + t] = f2bf(pgr[(size_t)g * 128 + t]);
  row[256 + t] = f2bf(nr[(size_t)fi * 128 + t]);
}

// WTf[c][fn][lane(lr,lg)][j] = W1col[fn*16+lr][c*32+lg*8+j]  (zero-pad k>=516)
// -> each wave B-frag load is one contiguous, coalesced 1KB read.
__global__ __launch_bounds__(256) void k_wt(const float* __restrict__ sW1,
                                            const float* __restrict__ tW1,
                                            u16* __restrict__ wtf) {
  int idx = blockIdx.x * 256 + threadIdx.x;
  if (idx >= 17 * 8 * 64 * 8) return;
  int j = idx & 7, l = (idx >> 3) & 63, fn = (idx >> 9) & 7, c = idx >> 12;
  int lr = l & 15, lg = l >> 4;
  int col = fn * 16 + lr;
  int k = c * 32 + lg * 8 + j;
  float v = 0.f;
  if (k < 516) v = (col < 64) ? sW1[(size_t)k * 64 + col] : tW1[(size_t)k * 64 + (col - 64)];
  wtf[idx] = f2bf(v);
}

__global__ __launch_bounds__(256) void k_misc(const float* __restrict__ nme,
                                              const float* __restrict__ sb1,
                                              const float* __restrict__ tb1,
                                              u16* __restrict__ nmebf,
                                              float* __restrict__ bias) {
  int t = threadIdx.x;
  if (t < 160) nmebf[t] = (t < 132) ? f2bf(nme[t]) : (u16)0;
  if (t < 64) bias[t] = sb1[t];
  else if (t < 128) bias[t] = tb1[t - 64];
}

// ---------- hybrid gather-GEMM: A via DMA-LDS ring, B direct-to-reg ----------
// 128 threads = 2 waves; wave tile 64 rows x 128 cols (acc 4x8). BK=32, 17
// chunks (K padded 544). A staged via global_load_lds into a 3-ring (8KB/chunk,
// each byte ds_read exactly once, XOR-swizzled conflict-free). B loaded from
// the L2-hot WTf as contiguous 1KB frags, double-buffered in regs. One barrier
// per step; counted vmcnt (12 = B(c)8 + stage(c+1)4 younger than stage(c));
// lgkmcnt(0) before barrier (rule 18: MFMA may sink past barrier, ds_reads
// must drain before another wave's DMA overwrites the ring).
__global__ __launch_bounds__(128, 2) void fused_mlp(
    const u16* __restrict__ NRbf, const u16* __restrict__ GFbf,
    const u16* __restrict__ WTf, const u16* __restrict__ NMEbf,
    const float* __restrict__ bias128,
    const int* __restrict__ tgt, const int* __restrict__ n2g,
    const float* __restrict__ feats, const float* __restrict__ dtab,
    const float* __restrict__ sW2, const float* __restrict__ sb2,
    const float* __restrict__ tW2, const float* __restrict__ tb2,
    float* __restrict__ out0, float* __restrict__ out1) {
  __shared__ uint4 ldsbuf[1536];  // 3 rings x 8KB = 24576 B
  char* const lds = (char*)ldsbuf;

  const int tid = threadIdx.x;
  const int l = tid & 63, w = tid >> 6;
  const int lr = l & 15, lg = l >> 4;
  const int row0b = blockIdx.x * 128;
  const int row0w = row0b + w * 64;
  const bool edge = (row0b < E_CNT);  // blocks homogeneous (400000 = 3125*128)

  // staging: issue j covers LDS rows j*32 + w*16 + rr; lane: row rr=l>>2,
  // dest slot l&3, source slot (l&3)^q with q=(row>>1)&3=(l>>3)&3
  const int rr = l >> 2;
  const int so = (((l & 3) ^ ((l >> 3) & 3)) << 4);
  const char *pGFs[4], *pNRs[4];
#pragma unroll
  for (int j = 0; j < 4; ++j) {
    int m = row0b + j * 32 + w * 16 + rr;
    if (edge) {
      int t = tgt[m];
      int g = n2g[t];
      pGFs[j] = (const char*)GFbf + (size_t)g * 768 + so;
      pNRs[j] = (const char*)NRbf + (size_t)t * 256 + so;
    } else {
      pGFs[j] = (const char*)GFbf + (size_t)(m - E_CNT) * 768 + so;
      pNRs[j] = (const char*)NMEbf + so;  // zero-padded to 320B
    }
  }
  const char* pWB = (const char*)WTf + l * 16;

  auto stageA = [&](int c2, int ring) {
#pragma unroll
    for (int j = 0; j < 4; ++j) {
      const char* src = (c2 < 12) ? pGFs[j] + c2 * 64 : pNRs[j] + (c2 - 12) * 64;
      gload16(src, lds + ring + j * 2048 + w * 1024);
    }
  };

  const int rdsw = ((lg ^ ((lr >> 1) & 3)) << 4);  // read-side swizzled slot

  f32x4 acc[4][8];
#pragma unroll
  for (int i = 0; i < 4; ++i)
#pragma unroll
    for (int j = 0; j < 8; ++j) acc[i][j] = (f32x4){0.f, 0.f, 0.f, 0.f};

  bf16x8 bbuf[2][8];

  stageA(0, 0);
  stageA(1, 8192);
  asm volatile("" ::: "memory");  // pin: stages before B(0)
#pragma unroll
  for (int fn = 0; fn < 8; ++fn)
    bbuf[0][fn] = *(const bf16x8*)(pWB + fn * 1024);

#pragma unroll
  for (int c = 0; c < 16; ++c) {
    // stage(c) complete for all waves; own ds_reads drained
    if (c < 15) asm volatile("s_waitcnt vmcnt(12) lgkmcnt(0)" ::: "memory");
    else        asm volatile("s_waitcnt vmcnt(8) lgkmcnt(0)" ::: "memory");
    __builtin_amdgcn_s_barrier();
    asm volatile("" ::: "memory");

    // B prefetch for c+1 (oldest-first order: B before stage)
#pragma unroll
    for (int fn = 0; fn < 8; ++fn)
      bbuf[(c + 1) & 1][fn] = *(const bf16x8*)(pWB + ((c + 1) * 8 + fn) * 1024);
    asm volatile("" ::: "memory");  // pin B(c+1) before stage(c+2)
    if (c < 14) stageA(c + 2, ((c + 2) % 3) * 8192);
    asm volatile("" ::: "memory");

    const int ring = (c % 3) * 8192;
    bf16x8 aF[4];
#pragma unroll
    for (int fm = 0; fm < 4; ++fm)
      aF[fm] = *(const bf16x8*)(lds + ring + (w * 64 + fm * 16 + lr) * 64 + rdsw);
#pragma unroll
    for (int fm = 0; fm < 4; ++fm)
#pragma unroll
      for (int fn = 0; fn < 8; ++fn)
        acc[fm][fn] = __builtin_amdgcn_mfma_f32_16x16x32_bf16(aF[fm], bbuf[c & 1][fn], acc[fm][fn], 0, 0, 0);
  }

  // ---- tail chunk c=16 (k 512..543): A built in registers, B(16) in bbuf[0]
#pragma unroll
  for (int fm = 0; fm < 4; ++fm) {
    union { u16 u[8]; bf16x8 v; } tt;
#pragma unroll
    for (int j = 0; j < 8; ++j) tt.u[j] = 0;
    if (lg == 0) {  // k=512..519: [dist_emb, f1, f2, f3, 0,0,0,0]
      if (edge) {
        const float4 f = *(const float4*)(feats + (size_t)(row0w + fm * 16 + lr) * 4);
        int td = (int)fminf(f.x, 9.0f);
        tt.u[0] = f2bf(dtab[td]); tt.u[1] = f2bf(f.y);
        tt.u[2] = f2bf(f.z);      tt.u[3] = f2bf(f.w);
      } else {
        tt.u[0] = NMEbf[128]; tt.u[1] = NMEbf[129];
        tt.u[2] = NMEbf[130]; tt.u[3] = NMEbf[131];
      }
    }
#pragma unroll
    for (int fn = 0; fn < 8; ++fn)
      acc[fm][fn] = __builtin_amdgcn_mfma_f32_16x16x32_bf16(tt.v, bbuf[0][fn], acc[fm][fn], 0, 0, 0);
  }

  // ---- epilogues. C layout: col = fn*16+lr, row = fm*16 + lg*4 + rg ----
  {  // scorer head: hidden cols 0..63 = fn 0..3
    float w2v[4], bb[4];
#pragma unroll
    for (int fn = 0; fn < 4; ++fn) {
      int hh = fn * 16 + lr;
      w2v[fn] = sW2[hh];
      bb[fn] = bias128[hh];
    }
    float b2 = sb2[0];
#pragma unroll
    for (int fm = 0; fm < 4; ++fm) {
      float p[4] = {0.f, 0.f, 0.f, 0.f};
#pragma unroll
      for (int fn = 0; fn < 4; ++fn)
#pragma unroll
        for (int rg = 0; rg < 4; ++rg)
          p[rg] += fmaxf(acc[fm][fn][rg] + bb[fn], 0.f) * w2v[fn];
#pragma unroll
      for (int rg = 0; rg < 4; ++rg)
#pragma unroll
        for (int m = 1; m < 16; m <<= 1) p[rg] += __shfl_xor(p[rg], m, 64);
      if (lr == 0) {
        int rbase = row0w + fm * 16 + lg * 4;
        *(float4*)(out0 + rbase) = make_float4(p[0] + b2, p[1] + b2, p[2] + b2, p[3] + b2);
      }
    }
  }
  if (edge) {  // type head: hidden cols 64..127 = fn 4..7
    float bb[4], tw0[4], tw1[4], tw2v[4];
#pragma unroll
    for (int fn = 0; fn < 4; ++fn) {
      int hh = fn * 16 + lr;
      bb[fn] = bias128[64 + hh];
      tw0[fn] = tW2[hh * 3 + 0];
      tw1[fn] = tW2[hh * 3 + 1];
      tw2v[fn] = tW2[hh * 3 + 2];
    }
    float tb0 = tb2[0], tb1 = tb2[1], tb2s = tb2[2];
#pragma unroll
    for (int fm = 0; fm < 4; ++fm) {
      float p0[4] = {0.f, 0.f, 0.f, 0.f}, p1[4] = {0.f, 0.f, 0.f, 0.f}, p2[4] = {0.f, 0.f, 0.f, 0.f};
#pragma unroll
      for (int fn = 0; fn < 4; ++fn)
#pragma unroll
        for (int rg = 0; rg < 4; ++rg) {
          float h = fmaxf(acc[fm][fn + 4][rg] + bb[fn], 0.f);
          p0[rg] += h * tw0[fn];
          p1[rg] += h * tw1[fn];
          p2[rg] += h * tw2v[fn];
        }
#pragma unroll
      for (int rg = 0; rg < 4; ++rg)
#pragma unroll
        for (int m = 1; m < 16; m <<= 1) {
          p0[rg] += __shfl_xor(p0[rg], m, 64);
          p1[rg] += __shfl_xor(p1[rg], m, 64);
          p2[rg] += __shfl_xor(p2[rg], m, 64);
        }
      if (lr == 0) {
        int rbase = row0w + fm * 16 + lg * 4;
        float* dst = out1 + (size_t)rbase * 3;  // 12 consecutive f32, 16B-aligned
        *(float4*)(dst + 0) = make_float4(p0[0] + tb0, p1[0] + tb1, p2[0] + tb2s, p0[1] + tb0);
        *(float4*)(dst + 4) = make_float4(p1[1] + tb1, p2[1] + tb2s, p0[2] + tb0, p1[2] + tb1);
        *(float4*)(dst + 8) = make_float4(p2[2] + tb2s, p0[3] + tb0, p1[3] + tb1, p2[3] + tb2s);
      }
    }
  }
}

extern "C" void kernel_launch(void* const* d_in, const int* in_sizes, int n_in,
                              void* d_out, int out_size, void* d_ws, size_t ws_size,
                              hipStream_t stream) {
  const float* imr   = (const float*)d_in[0];
  const float* pgr   = (const float*)d_in[1];
  const float* nr    = (const float*)d_in[2];
  const int*   focus = (const int*)d_in[3];
  const int*   n2g   = (const int*)d_in[4];
  const int*   tgt   = (const int*)d_in[5];
  const float* feats = (const float*)d_in[6];
  const float* dtab  = (const float*)d_in[8];
  const float* nme   = (const float*)d_in[9];
  const float* sW1   = (const float*)d_in[10];
  const float* sb1   = (const float*)d_in[11];
  const float* sW2   = (const float*)d_in[12];
  const float* sb2   = (const float*)d_in[13];
  const float* tW1   = (const float*)d_in[14];
  const float* tb1   = (const float*)d_in[15];
  const float* tW2   = (const float*)d_in[16];
  const float* tb2   = (const float*)d_in[17];

  char* ws = (char*)d_ws;
  u16*   NRbf  = (u16*)(ws + WS_NRBF);
  u16*   GFbf  = (u16*)(ws + WS_GFBF);
  u16*   WTf   = (u16*)(ws + WS_WTF);
  u16*   NMEbf = (u16*)(ws + WS_NME);
  float* bias  = (float*)(ws + WS_BIAS);

  float* out0 = (float*)d_out;          // [401024]
  float* out1 = out0 + NROWS;           // [400000*3]

  k_conv_nr<<<8192, 256, 0, stream>>>((const float4*)nr, NRbf);
  k_gf<<<1024, 128, 0, stream>>>(imr, pgr, nr, focus, GFbf);
  k_wt<<<272, 256, 0, stream>>>(sW1, tW1, WTf);
  k_misc<<<1, 256, 0, stream>>>(nme, sb1, tb1, NMEbf, bias);
  fused_mlp<<<NBLK, 128, 0, stream>>>(NRbf, GFbf, WTf, NMEbf, bias, tgt, n2g, feats,
                                      dtab, sW2, sb2, tW2, tb2, out0, out1);
}